// Round 7
// baseline (3439.990 us; speedup 1.0000x reference)
//
#include <hip/hip_runtime.h>
#include <hip/hip_bf16.h>

namespace {

typedef _Float16 h16;
typedef _Float16 f16x8 __attribute__((ext_vector_type(8)));
typedef _Float16 f16x4 __attribute__((ext_vector_type(4)));
typedef _Float16 f16x2 __attribute__((ext_vector_type(2)));
typedef float    f32x4 __attribute__((ext_vector_type(4)));
typedef unsigned long long u64;

constexpr int T_SEQ = 512;
constexpr int B_SZ  = 1024;
constexpr int H_DIM = 128;
constexpr int ROWS  = 16;           // batch rows per group (MFMA N-tile)
constexpr int NT    = 512;          // 8 waves (2/SIMD: latency hiding, round-5 verified)
constexpr int NGRP  = B_SZ / ROWS;  // 64 groups -> 128 blocks (producer+consumer)

// Fused 2-layer pipeline. Producer block g runs layer-0 for batch group g and
// publishes h1(g,t) via agent-scope atomics + a flag every 4 steps; consumer
// block g runs layer-1 one~four steps behind. 128 blocks on 256 CUs.
template <int INDIM, bool PROD>
__device__ void gru_body(char* smem_raw,
                         const float* __restrict__ xin,   // PROD: x [B][T][64] f32
                         const float* __restrict__ w_ih,  // [384][INDIM]
                         const float* __restrict__ w_hh,  // [384][128]
                         const float* __restrict__ b_ih,
                         const float* __restrict__ b_hh,
                         u64* __restrict__ h1q,           // [T][B][32] u64 (= [T][B][128] f16)
                         int* __restrict__ flag,          // this group's flag
                         float* __restrict__ h2out,       // consumer: [B][128]
                         const int g)
{
  constexpr int KSH  = H_DIM / 32;       // 4
  constexpr int KSX  = INDIM / 32;       // 2 (l0) / 4 (l1)
  constexpr int ROWP = H_DIM + INDIM + 4; // stride ==2 mod 32 dwords: conflict-free (r6-verified)

  auto hx = reinterpret_cast<h16 (*)[ROWS][ROWP]>(smem_raw);  // hx[2][ROWS][ROWP]

  const int tid = threadIdx.x;
  const int wv  = tid >> 6;        // wave 0..7 -> 16-gate-col group
  const int ln  = tid & 63;
  const int q   = ln >> 4;
  const int lr  = ln & 15;         // A: gate row in tile; B/D: batch col
  const int r0  = g * ROWS;
  const int j0  = wv * 16 + q * 4;

  // ---- weights -> fp16 frags, once (round-4/5 verified layout) ----
  f16x8 wA[3][KSH], wB[3][KSX];
  #pragma unroll
  for (int p = 0; p < 3; ++p) {
    const int gr = p * H_DIM + wv * 16 + lr;
    #pragma unroll
    for (int ks = 0; ks < KSH; ++ks) {
      const float* pw = w_hh + (size_t)gr * H_DIM + ks * 32 + q * 8;
      const float4 v0 = *(const float4*)(pw);
      const float4 v1 = *(const float4*)(pw + 4);
      f16x8 f;
      f[0]=(h16)v0.x; f[1]=(h16)v0.y; f[2]=(h16)v0.z; f[3]=(h16)v0.w;
      f[4]=(h16)v1.x; f[5]=(h16)v1.y; f[6]=(h16)v1.z; f[7]=(h16)v1.w;
      wA[p][ks] = f;
    }
    #pragma unroll
    for (int ks = 0; ks < KSX; ++ks) {
      const float* pw = w_ih + (size_t)gr * INDIM + ks * 32 + q * 8;
      const float4 v0 = *(const float4*)(pw);
      const float4 v1 = *(const float4*)(pw + 4);
      f16x8 f;
      f[0]=(h16)v0.x; f[1]=(h16)v0.y; f[2]=(h16)v0.z; f[3]=(h16)v0.w;
      f[4]=(h16)v1.x; f[5]=(h16)v1.y; f[6]=(h16)v1.z; f[7]=(h16)v1.w;
      wB[p][ks] = f;
    }
  }

  // ---- biases folded into MFMA C-init ----
  f32x4 bR, bZ, bNx, bNh;
  {
    const float4 ir  = *(const float4*)&b_ih[j0];
    const float4 hr  = *(const float4*)&b_hh[j0];
    const float4 iz  = *(const float4*)&b_ih[H_DIM + j0];
    const float4 hz  = *(const float4*)&b_hh[H_DIM + j0];
    const float4 in_ = *(const float4*)&b_ih[2 * H_DIM + j0];
    const float4 hn  = *(const float4*)&b_hh[2 * H_DIM + j0];
    bR[0]=ir.x+hr.x; bR[1]=ir.y+hr.y; bR[2]=ir.z+hr.z; bR[3]=ir.w+hr.w;
    bZ[0]=iz.x+hz.x; bZ[1]=iz.y+hz.y; bZ[2]=iz.z+hz.z; bZ[3]=iz.w+hz.w;
    bNx[0]=in_.x; bNx[1]=in_.y; bNx[2]=in_.z; bNx[3]=in_.w;
    bNh[0]=hn.x;  bNh[1]=hn.y;  bNh[2]=hn.z;  bNh[3]=hn.w;
  }

  const int sr = tid >> 5;   // 0..15
  const int si = tid & 31;   // 0..31

  // ---- prologue: zero h-part of buf0; stage in(0) ----
  {
    f16x4 z; z[0]=z[1]=z[2]=z[3] = (h16)0.f;
    *(f16x4*)&hx[0][sr][si * 4] = z;     // 16 x 128 h16 zeroed
  }
  f16x4 h_old; h_old[0]=h_old[1]=h_old[2]=h_old[3] = (h16)0.f;

  f16x2 sA, sB;                          // producer x-prefetch ping-pong
  if constexpr (PROD) {
    const float2 v0 = *(const float2*)(xin + ((size_t)(r0 + sr) * T_SEQ + 0) * 64 + si * 2);
    f16x2 s0; s0[0] = (h16)v0.x; s0[1] = (h16)v0.y;
    *(f16x2*)&hx[0][sr][H_DIM + si * 2] = s0;
    const float2 v1 = *(const float2*)(xin + ((size_t)(r0 + sr) * T_SEQ + 1) * 64 + si * 2);
    sA[0] = (h16)v1.x; sA[1] = (h16)v1.y;
  } else {
    while (__hip_atomic_load(flag, __ATOMIC_ACQUIRE, __HIP_MEMORY_SCOPE_AGENT) < 1) {}
    const u64 bits = __hip_atomic_load(&h1q[((size_t)0 * B_SZ + r0 + sr) * 32 + si],
                                       __ATOMIC_RELAXED, __HIP_MEMORY_SCOPE_AGENT);
    f16x4 s0; __builtin_memcpy(&s0, &bits, 8);
    *(f16x4*)&hx[0][sr][H_DIM + si * 4] = s0;
  }
  __syncthreads();

  // ---- shared gate math ----
  auto gates = [&](const f32x4& aR, const f32x4& aZ, const f32x4& aNx2, const f32x4& aNh2,
                   f16x4& nv4, float* hnv) {
    #pragma unroll
    for (int i = 0; i < 4; ++i) {
      const float rg = __builtin_amdgcn_rcpf(1.f + __expf(-aR[i]));
      const float zg = __builtin_amdgcn_rcpf(1.f + __expf(-aZ[i]));
      const float na = aNx2[i] + rg * aNh2[i];
      const float e2 = __expf(2.f * na);
      const float ng = 1.f - 2.f * __builtin_amdgcn_rcpf(e2 + 1.f);
      const float ho = (float)h_old[i];
      const float hn = ng + zg * (ho - ng);
      hnv[i] = hn;
      nv4[i] = (h16)hn;
    }
    h_old = nv4;
  };

  if constexpr (PROD) {
    auto pstep = [&](int t, int cur, f16x2& s_use, f16x2& s_load) {
      f16x8 bh[KSH], bx[KSX];
      #pragma unroll
      for (int ks = 0; ks < KSH; ++ks) bh[ks] = *(const f16x8*)&hx[cur][lr][ks * 32 + q * 8];
      #pragma unroll
      for (int ks = 0; ks < KSX; ++ks) bx[ks] = *(const f16x8*)&hx[cur][lr][H_DIM + ks * 32 + q * 8];

      {  // prefetch x(t+2), 2-deep
        const int tt = (t + 2 < T_SEQ) ? t + 2 : T_SEQ - 1;
        const float2 v = *(const float2*)(xin + ((size_t)(r0 + sr) * T_SEQ + tt) * 64 + si * 2);
        s_load[0] = (h16)v.x; s_load[1] = (h16)v.y;
      }

      f32x4 aR = bR, aZ = bZ, aNh2 = bNh, aNx2 = bNx;
      #pragma unroll
      for (int ks = 0; ks < KSH; ++ks) {
        aR   = __builtin_amdgcn_mfma_f32_16x16x32_f16(wA[0][ks], bh[ks], aR, 0, 0, 0);
        aZ   = __builtin_amdgcn_mfma_f32_16x16x32_f16(wA[1][ks], bh[ks], aZ, 0, 0, 0);
        aNh2 = __builtin_amdgcn_mfma_f32_16x16x32_f16(wA[2][ks], bh[ks], aNh2, 0, 0, 0);
      }
      #pragma unroll
      for (int ks = 0; ks < KSX; ++ks) {
        aR   = __builtin_amdgcn_mfma_f32_16x16x32_f16(wB[0][ks], bx[ks], aR, 0, 0, 0);
        aZ   = __builtin_amdgcn_mfma_f32_16x16x32_f16(wB[1][ks], bx[ks], aZ, 0, 0, 0);
        aNx2 = __builtin_amdgcn_mfma_f32_16x16x32_f16(wB[2][ks], bx[ks], aNx2, 0, 0, 0);
      }

      f16x4 nv4; float hnv[4];
      gates(aR, aZ, aNx2, aNh2, nv4, hnv);

      // publish h1(t): agent-scope write-through (8B/lane, exactly covers tile)
      u64 bits; __builtin_memcpy(&bits, &nv4, 8);
      __hip_atomic_store(&h1q[((size_t)t * B_SZ + r0 + lr) * 32 + (j0 >> 2)], bits,
                         __ATOMIC_RELAXED, __HIP_MEMORY_SCOPE_AGENT);

      *(f16x4*)&hx[cur ^ 1][lr][j0] = nv4;
      *(f16x2*)&hx[cur ^ 1][sr][H_DIM + si * 2] = s_use;

      if ((t & 3) == 3) __threadfence();   // all lanes' stores (steps t-3..t) complete
      __syncthreads();
      if (((t & 3) == 3) && tid == 0)
        __hip_atomic_store(flag, t + 1, __ATOMIC_RELEASE, __HIP_MEMORY_SCOPE_AGENT);
    };

    #pragma unroll 1
    for (int t = 0; t < T_SEQ; t += 2) {
      pstep(t,     0, sA, sB);
      pstep(t + 1, 1, sB, sA);
    }
  } else {
    #pragma unroll 1
    for (int t = 0; t < T_SEQ; ++t) {
      const int cur = t & 1;
      f16x8 bh[KSH], bx[KSX];
      #pragma unroll
      for (int ks = 0; ks < KSH; ++ks) bh[ks] = *(const f16x8*)&hx[cur][lr][ks * 32 + q * 8];
      #pragma unroll
      for (int ks = 0; ks < KSX; ++ks) bx[ks] = *(const f16x8*)&hx[cur][lr][H_DIM + ks * 32 + q * 8];

      // prefetch h1(t+1): spin (amortized; flag jumps by 4), then 8B atomic load
      f16x4 sN;
      const bool have = (t + 1 < T_SEQ);
      if (have) {
        while (__hip_atomic_load(flag, __ATOMIC_ACQUIRE, __HIP_MEMORY_SCOPE_AGENT) < t + 2) {}
        const u64 bits = __hip_atomic_load(&h1q[((size_t)(t + 1) * B_SZ + r0 + sr) * 32 + si],
                                           __ATOMIC_RELAXED, __HIP_MEMORY_SCOPE_AGENT);
        __builtin_memcpy(&sN, &bits, 8);
      }

      f32x4 aR = bR, aZ = bZ, aNh2 = bNh, aNx2 = bNx;
      #pragma unroll
      for (int ks = 0; ks < KSH; ++ks) {
        aR   = __builtin_amdgcn_mfma_f32_16x16x32_f16(wA[0][ks], bh[ks], aR, 0, 0, 0);
        aZ   = __builtin_amdgcn_mfma_f32_16x16x32_f16(wA[1][ks], bh[ks], aZ, 0, 0, 0);
        aNh2 = __builtin_amdgcn_mfma_f32_16x16x32_f16(wA[2][ks], bh[ks], aNh2, 0, 0, 0);
      }
      #pragma unroll
      for (int ks = 0; ks < KSX; ++ks) {
        aR   = __builtin_amdgcn_mfma_f32_16x16x32_f16(wB[0][ks], bx[ks], aR, 0, 0, 0);
        aZ   = __builtin_amdgcn_mfma_f32_16x16x32_f16(wB[1][ks], bx[ks], aZ, 0, 0, 0);
        aNx2 = __builtin_amdgcn_mfma_f32_16x16x32_f16(wB[2][ks], bx[ks], aNx2, 0, 0, 0);
      }

      f16x4 nv4; float hnv[4];
      gates(aR, aZ, aNx2, aNh2, nv4, hnv);

      *(f16x4*)&hx[cur ^ 1][lr][j0] = nv4;
      if (have) *(f16x4*)&hx[cur ^ 1][sr][H_DIM + si * 4] = sN;
      if (t == T_SEQ - 1)
        *(float4*)&h2out[(size_t)(r0 + lr) * H_DIM + j0] =
            make_float4(hnv[0], hnv[1], hnv[2], hnv[3]);
      __syncthreads();
    }
  }
}

__global__ __launch_bounds__(NT, 2)
void gru_fused(const float* __restrict__ x,
               const float* __restrict__ w_ih0, const float* __restrict__ w_hh0,
               const float* __restrict__ b_ih0, const float* __restrict__ b_hh0,
               const float* __restrict__ w_ih1, const float* __restrict__ w_hh1,
               const float* __restrict__ b_ih1, const float* __restrict__ b_hh1,
               u64* __restrict__ h1q, int* __restrict__ flags, float* __restrict__ h2)
{
  __shared__ __align__(16) char smem[(size_t)2 * ROWS * (H_DIM + H_DIM + 4) * sizeof(h16)];
  const int bid = blockIdx.x;
  if (bid < NGRP)
    gru_body<64, true>(smem, x, w_ih0, w_hh0, b_ih0, b_hh0, h1q, &flags[bid], nullptr, bid);
  else
    gru_body<128, false>(smem, nullptr, w_ih1, w_hh1, b_ih1, b_hh1, h1q,
                         &flags[bid - NGRP], h2, bid - NGRP);
}

// FC head: out = fc2( BN( relu( fc1(h2_last) ) ) ); one row per block.
__global__ __launch_bounds__(64)
void head_kernel(const float* __restrict__ h2,
                 const float* __restrict__ fc1_w, const float* __restrict__ fc1_b,
                 const float* __restrict__ fc2_w, const float* __restrict__ fc2_b,
                 const float* __restrict__ gamma, const float* __restrict__ beta,
                 const float* __restrict__ mean,  const float* __restrict__ var,
                 float* __restrict__ out)
{
  const int row = blockIdx.x;
  const int j   = threadIdx.x;
  __shared__ __align__(16) float hrow[H_DIM];
  __shared__ __align__(16) float act[64];

  hrow[j]      = h2[(size_t)row * H_DIM + j];
  hrow[64 + j] = h2[(size_t)row * H_DIM + 64 + j];
  __syncthreads();

  float s = fc1_b[j];
  const float4* wr = reinterpret_cast<const float4*>(fc1_w + (size_t)j * H_DIM);
  #pragma unroll
  for (int k4 = 0; k4 < H_DIM / 4; ++k4) {
    const float4 w = wr[k4];
    const float4 h = reinterpret_cast<const float4*>(hrow)[k4];
    s += w.x * h.x + w.y * h.y + w.z * h.z + w.w * h.w;
  }
  s = fmaxf(s, 0.f);
  s = (s - mean[j]) * rsqrtf(var[j] + 1e-5f) * gamma[j] + beta[j];
  act[j] = s;
  __syncthreads();

  if (j < 2) {
    float o = fc2_b[j];
    #pragma unroll
    for (int k = 0; k < 64; ++k) o += fc2_w[(size_t)j * 64 + k] * act[k];
    out[(size_t)row * 2 + j] = o;
  }
}

} // namespace

extern "C" void kernel_launch(void* const* d_in, const int* in_sizes, int n_in,
                              void* d_out, int out_size, void* d_ws, size_t ws_size,
                              hipStream_t stream) {
  const float* x     = (const float*)d_in[0];
  const float* w_ih0 = (const float*)d_in[1];
  const float* w_hh0 = (const float*)d_in[2];
  const float* b_ih0 = (const float*)d_in[3];
  const float* b_hh0 = (const float*)d_in[4];
  const float* w_ih1 = (const float*)d_in[5];
  const float* w_hh1 = (const float*)d_in[6];
  const float* b_ih1 = (const float*)d_in[7];
  const float* b_hh1 = (const float*)d_in[8];
  const float* fc1_w = (const float*)d_in[9];
  const float* fc1_b = (const float*)d_in[10];
  const float* fc2_w = (const float*)d_in[11];
  const float* fc2_b = (const float*)d_in[12];
  const float* gamma = (const float*)d_in[13];
  const float* beta  = (const float*)d_in[14];
  const float* mean  = (const float*)d_in[15];
  const float* var   = (const float*)d_in[16];
  float* out = (float*)d_out;

  char* ws = (char*)d_ws;
  const size_t h2_bytes = (size_t)B_SZ * H_DIM * sizeof(float);            // 512 KB
  const size_t h1_bytes = (size_t)T_SEQ * B_SZ * H_DIM * sizeof(h16);      // 134 MB
  const size_t fl_bytes = (size_t)NGRP * sizeof(int);
  if (ws_size < h2_bytes + h1_bytes + fl_bytes) return;  // fail visibly

  float* h2    = (float*)ws;
  u64*   h1q   = (u64*)(ws + h2_bytes);
  int*   flags = (int*)(ws + h2_bytes + h1_bytes);

  hipMemsetAsync(flags, 0, fl_bytes, stream);   // flags must start at 0 each replay
  gru_fused<<<dim3(2 * NGRP), dim3(NT), 0, stream>>>(
      x, w_ih0, w_hh0, b_ih0, b_hh0, w_ih1, w_hh1, b_ih1, b_hh1, h1q, flags, h2);
  head_kernel<<<dim3(B_SZ), dim3(64), 0, stream>>>(
      h2, fc1_w, fc1_b, fc2_w, fc2_b, gamma, beta, mean, var, out);
}

// Round 8
// 779.000 us; speedup vs baseline: 4.4159x; 4.4159x over previous
//
#include <hip/hip_runtime.h>
#include <hip/hip_bf16.h>

namespace {

typedef _Float16 h16;
typedef _Float16 f16x8 __attribute__((ext_vector_type(8)));
typedef _Float16 f16x4 __attribute__((ext_vector_type(4)));
typedef _Float16 f16x2 __attribute__((ext_vector_type(2)));
typedef float    f32x4 __attribute__((ext_vector_type(4)));

constexpr int T_SEQ = 512;
constexpr int B_SZ  = 1024;
constexpr int H_DIM = 128;
constexpr int ROWS  = 16;    // batch rows per block (MFMA N-tile)
constexpr int NT    = 512;   // 8 waves (2/SIMD — round-5/6 A/B: needed for latency hiding)

// LDS-only barrier: waves drain their own ds ops (lgkmcnt) then rendezvous.
// Unlike __syncthreads(), does NOT drain vmcnt -> the 2-step-deep global
// prefetch stays in flight across the barrier (compiler still inserts the
// vmcnt wait at the loaded register's USE point, one step later).
__device__ __forceinline__ void lds_barrier() {
  asm volatile("s_waitcnt lgkmcnt(0)\n\ts_barrier" ::: "memory");
}

// Persistent MFMA GRU layer (round-5 structure + pad fix + lds_barrier):
//  - 8 waves; hx double-buffered -> ONE barrier per step
//  - h_old in registers (producing lane == consuming lane)
//  - input prefetch 2 steps deep (statically named regs)
//  - biases folded into MFMA C-init
//  - ROWP = KTOT+4 -> row stride == 2 mod 32 dwords: every LDS pattern is
//    <=2 lanes/bank (free); round-6 HW-verified (conflicts 7.3M -> 2K)
// Frag convention verified on HW (rounds 4-6, absmax 1.2e-4):
//  A row = lane&15 (gate within tile), k = (lane>>4)*8 + e + 32*ks
//  B col = lane&15 (batch),  same k;   D: col = lane&15, row = (lane>>4)*4+i
template <int INDIM, typename InT, bool STORE_ALL>
__global__ __launch_bounds__(NT, 1)
void gru_mfma(const InT* __restrict__ in,     // l0: x [B][T][64] f32; l1: h1 [T][B][128] f16
              const float* __restrict__ w_ih, // [384][INDIM]
              const float* __restrict__ w_hh, // [384][128]
              const float* __restrict__ b_ih, // [384]
              const float* __restrict__ b_hh, // [384]
              h16*  __restrict__ h1out,       // [T][B][128]   (STORE_ALL)
              float* __restrict__ h2out)      // [B][128]      (!STORE_ALL)
{
  constexpr int KSH  = H_DIM / 32;     // 4 K-steps over h
  constexpr int KSX  = INDIM / 32;     // 2 (l0) or 4 (l1) K-steps over input
  constexpr int KTOT = H_DIM + INDIM;
  constexpr int ROWP = KTOT + 4;       // stride: l0 196 h16 (98dw), l1 260 (130dw); ==2 mod 32

  __shared__ __align__(16) h16 hx[2][ROWS][ROWP];  // [buf][batch][h(128) | in(INDIM) | pad]

  const int tid = threadIdx.x;
  const int wv  = tid >> 6;        // wave 0..7 -> 16-gate-col group
  const int ln  = tid & 63;
  const int q   = ln >> 4;         // k-chunk / D-row group
  const int lr  = ln & 15;         // A: gate row within tile; B/D: batch col
  const int r0  = blockIdx.x * ROWS;
  const int j0  = wv * 16 + q * 4; // first of this lane's 4 gate cols

  // ---- weights -> fp16 frags, once ----
  f16x8 wA[3][KSH];   // w_hh rows (recurrent GEMM A-operand)
  f16x8 wB[3][KSX];   // w_ih rows (input GEMM A-operand)
  #pragma unroll
  for (int p = 0; p < 3; ++p) {
    const int g = p * H_DIM + wv * 16 + lr;
    #pragma unroll
    for (int ks = 0; ks < KSH; ++ks) {
      const float* pw = w_hh + (size_t)g * H_DIM + ks * 32 + q * 8;
      const float4 v0 = *(const float4*)(pw);
      const float4 v1 = *(const float4*)(pw + 4);
      f16x8 f;
      f[0]=(h16)v0.x; f[1]=(h16)v0.y; f[2]=(h16)v0.z; f[3]=(h16)v0.w;
      f[4]=(h16)v1.x; f[5]=(h16)v1.y; f[6]=(h16)v1.z; f[7]=(h16)v1.w;
      wA[p][ks] = f;
    }
    #pragma unroll
    for (int ks = 0; ks < KSX; ++ks) {
      const float* pw = w_ih + (size_t)g * INDIM + ks * 32 + q * 8;
      const float4 v0 = *(const float4*)(pw);
      const float4 v1 = *(const float4*)(pw + 4);
      f16x8 f;
      f[0]=(h16)v0.x; f[1]=(h16)v0.y; f[2]=(h16)v0.z; f[3]=(h16)v0.w;
      f[4]=(h16)v1.x; f[5]=(h16)v1.y; f[6]=(h16)v1.z; f[7]=(h16)v1.w;
      wB[p][ks] = f;
    }
  }

  // ---- bias C-init vectors for this lane's 4 gate cols ----
  f32x4 bR, bZ, bNx, bNh;
  {
    const float4 ir  = *(const float4*)&b_ih[j0];
    const float4 hr  = *(const float4*)&b_hh[j0];
    const float4 iz  = *(const float4*)&b_ih[H_DIM + j0];
    const float4 hz  = *(const float4*)&b_hh[H_DIM + j0];
    const float4 in_ = *(const float4*)&b_ih[2 * H_DIM + j0];
    const float4 hn  = *(const float4*)&b_hh[2 * H_DIM + j0];
    bR[0]=ir.x+hr.x; bR[1]=ir.y+hr.y; bR[2]=ir.z+hr.z; bR[3]=ir.w+hr.w;
    bZ[0]=iz.x+hz.x; bZ[1]=iz.y+hz.y; bZ[2]=iz.z+hz.z; bZ[3]=iz.w+hz.w;
    bNx[0]=in_.x; bNx[1]=in_.y; bNx[2]=in_.z; bNx[3]=in_.w;
    bNh[0]=hn.x;  bNh[1]=hn.y;  bNh[2]=hn.z;  bNh[3]=hn.w;
  }

  // ---- staging ids: thread -> (batch row sr, chunk si) ----
  const int sr = tid >> 5;         // 0..15
  const int si = tid & 31;         // 0..31

  auto load_stage = [&](int t, f16x4& dst) {
    if constexpr (INDIM == 64) {   // x [B][T][64] f32 -> convert inline (f16x2 used)
      const float2 v = *(const float2*)(in + ((size_t)(r0 + sr) * T_SEQ + t) * 64 + si * 2);
      dst[0] = (h16)v.x; dst[1] = (h16)v.y;
    } else {                       // h1 [T][B][128] f16
      dst = *(const f16x4*)(in + ((size_t)t * B_SZ + (r0 + sr)) * 128 + si * 4);
    }
  };
  auto write_stage = [&](int buf, const f16x4& s) {
    if constexpr (INDIM == 64) {
      f16x2 v; v[0] = s[0]; v[1] = s[1];
      *(f16x2*)&hx[buf][sr][H_DIM + si * 2] = v;
    } else {
      *(f16x4*)&hx[buf][sr][H_DIM + si * 4] = s;
    }
  };

  // ---- prologue: h(0)=0 and in(0) into buf 0; in(1) into regs ----
  {
    const int zr = tid >> 5, zc = (tid & 31) * 4;   // 16 x 128 h16 = 512 x f16x4
    f16x4 z; z[0] = z[1] = z[2] = z[3] = (h16)0.f;
    *(f16x4*)&hx[0][zr][zc] = z;
  }
  f16x4 s0; load_stage(0, s0); write_stage(0, s0);
  f16x4 sA; load_stage(1, sA);    // in(1), written during step 0
  f16x4 sB;                       // in(2), loaded during step 0
  f16x4 h_old; h_old[0] = h_old[1] = h_old[2] = h_old[3] = (h16)0.f;
  __syncthreads();

  auto step = [&](int t, int cur, f16x4& s_use, f16x4& s_load) {
    // B-frags from hx[cur] (conflict-free per pad analysis)
    f16x8 bh[KSH], bx[KSX];
    #pragma unroll
    for (int ks = 0; ks < KSH; ++ks)
      bh[ks] = *(const f16x8*)&hx[cur][lr][ks * 32 + q * 8];
    #pragma unroll
    for (int ks = 0; ks < KSX; ++ks)
      bx[ks] = *(const f16x8*)&hx[cur][lr][H_DIM + ks * 32 + q * 8];

    // prefetch in(t+2) — stays in flight across the lds_barrier
    load_stage((t + 2 < T_SEQ) ? t + 2 : T_SEQ - 1, s_load);

    // MFMA: 4 independent chains, biases pre-loaded as C-init
    f32x4 aR = bR, aZ = bZ, aNh = bNh, aNx = bNx;
    #pragma unroll
    for (int ks = 0; ks < KSH; ++ks) {
      aR  = __builtin_amdgcn_mfma_f32_16x16x32_f16(wA[0][ks], bh[ks], aR, 0, 0, 0);
      aZ  = __builtin_amdgcn_mfma_f32_16x16x32_f16(wA[1][ks], bh[ks], aZ, 0, 0, 0);
      aNh = __builtin_amdgcn_mfma_f32_16x16x32_f16(wA[2][ks], bh[ks], aNh, 0, 0, 0);
    }
    #pragma unroll
    for (int ks = 0; ks < KSX; ++ks) {
      aR  = __builtin_amdgcn_mfma_f32_16x16x32_f16(wB[0][ks], bx[ks], aR, 0, 0, 0);
      aZ  = __builtin_amdgcn_mfma_f32_16x16x32_f16(wB[1][ks], bx[ks], aZ, 0, 0, 0);
      aNx = __builtin_amdgcn_mfma_f32_16x16x32_f16(wB[2][ks], bx[ks], aNx, 0, 0, 0);
    }

    // gates, fully in-lane; h_old is this lane's own previous output
    f16x4 nv4;
    float hnv[4];
    #pragma unroll
    for (int i = 0; i < 4; ++i) {
      const float rg = __builtin_amdgcn_rcpf(1.f + __expf(-aR[i]));
      const float zg = __builtin_amdgcn_rcpf(1.f + __expf(-aZ[i]));
      const float na = aNx[i] + rg * aNh[i];
      const float e2 = __expf(2.f * na);
      const float ng = 1.f - 2.f * __builtin_amdgcn_rcpf(e2 + 1.f);
      const float ho = (float)h_old[i];
      const float hn = ng + zg * (ho - ng);
      hnv[i] = hn;
      nv4[i] = (h16)hn;
    }
    h_old = nv4;

    // writes go to the OTHER buffer — no race with this step's readers
    *(f16x4*)&hx[cur ^ 1][lr][j0] = nv4;
    write_stage(cur ^ 1, s_use);
    if constexpr (STORE_ALL) {
      *(f16x4*)&h1out[((size_t)t * B_SZ + r0 + lr) * H_DIM + j0] = nv4;
    } else {
      if (t == T_SEQ - 1)
        *(float4*)&h2out[(size_t)(r0 + lr) * H_DIM + j0] =
            make_float4(hnv[0], hnv[1], hnv[2], hnv[3]);
    }
    lds_barrier();   // LDS-only: global prefetch stays outstanding
  };

  #pragma unroll 1
  for (int t = 0; t < T_SEQ; t += 2) {
    step(t,     0, sA, sB);   // reads buf0, writes buf1
    step(t + 1, 1, sB, sA);   // reads buf1, writes buf0
  }
}

// FC head: out = fc2( BN( relu( fc1(h2_last) ) ) ); one row per block.
__global__ __launch_bounds__(64)
void head_kernel(const float* __restrict__ h2,     // (B, H) f32
                 const float* __restrict__ fc1_w,  // (64, 128)
                 const float* __restrict__ fc1_b,  // (64)
                 const float* __restrict__ fc2_w,  // (2, 64)
                 const float* __restrict__ fc2_b,  // (2)
                 const float* __restrict__ gamma,
                 const float* __restrict__ beta,
                 const float* __restrict__ mean,
                 const float* __restrict__ var,
                 float* __restrict__ out)          // (B, 2)
{
  const int row = blockIdx.x;
  const int j   = threadIdx.x;   // 0..63
  __shared__ __align__(16) float hrow[H_DIM];
  __shared__ __align__(16) float act[64];

  hrow[j]      = h2[(size_t)row * H_DIM + j];
  hrow[64 + j] = h2[(size_t)row * H_DIM + 64 + j];
  __syncthreads();

  float s = fc1_b[j];
  const float4* wr = reinterpret_cast<const float4*>(fc1_w + (size_t)j * H_DIM);
  #pragma unroll
  for (int k4 = 0; k4 < H_DIM / 4; ++k4) {
    const float4 w = wr[k4];
    const float4 h = reinterpret_cast<const float4*>(hrow)[k4];
    s += w.x * h.x + w.y * h.y + w.z * h.z + w.w * h.w;
  }
  s = fmaxf(s, 0.f);
  s = (s - mean[j]) * rsqrtf(var[j] + 1e-5f) * gamma[j] + beta[j];
  act[j] = s;
  __syncthreads();

  if (j < 2) {
    float o = fc2_b[j];
    #pragma unroll
    for (int k = 0; k < 64; ++k) o += fc2_w[(size_t)j * 64 + k] * act[k];
    out[(size_t)row * 2 + j] = o;
  }
}

} // namespace

extern "C" void kernel_launch(void* const* d_in, const int* in_sizes, int n_in,
                              void* d_out, int out_size, void* d_ws, size_t ws_size,
                              hipStream_t stream) {
  const float* x     = (const float*)d_in[0];
  const float* w_ih0 = (const float*)d_in[1];
  const float* w_hh0 = (const float*)d_in[2];
  const float* b_ih0 = (const float*)d_in[3];
  const float* b_hh0 = (const float*)d_in[4];
  const float* w_ih1 = (const float*)d_in[5];
  const float* w_hh1 = (const float*)d_in[6];
  const float* b_ih1 = (const float*)d_in[7];
  const float* b_hh1 = (const float*)d_in[8];
  const float* fc1_w = (const float*)d_in[9];
  const float* fc1_b = (const float*)d_in[10];
  const float* fc2_w = (const float*)d_in[11];
  const float* fc2_b = (const float*)d_in[12];
  const float* gamma = (const float*)d_in[13];
  const float* beta  = (const float*)d_in[14];
  const float* mean  = (const float*)d_in[15];
  const float* var   = (const float*)d_in[16];
  float* out = (float*)d_out;

  char* ws = (char*)d_ws;
  const size_t h2_bytes = (size_t)B_SZ * H_DIM * sizeof(float);           // 512 KB
  const size_t h1_bytes = (size_t)T_SEQ * B_SZ * H_DIM * sizeof(h16);     // 134 MB
  if (ws_size < h2_bytes + h1_bytes) return;  // fail visibly

  float* h2 = (float*)ws;
  h16*   h1 = (h16*)(ws + h2_bytes);

  gru_mfma<64, float, true><<<dim3(B_SZ / ROWS), dim3(NT), 0, stream>>>(
      x, w_ih0, w_hh0, b_ih0, b_hh0, h1, nullptr);
  gru_mfma<128, h16, false><<<dim3(B_SZ / ROWS), dim3(NT), 0, stream>>>(
      h1, w_ih1, w_hh1, b_ih1, b_hh1, nullptr, h2);
  head_kernel<<<dim3(B_SZ), dim3(64), 0, stream>>>(
      h2, fc1_w, fc1_b, fc2_w, fc2_b, gamma, beta, mean, var, out);
}

// Round 9
// 701.983 us; speedup vs baseline: 4.9004x; 1.1097x over previous
//
#include <hip/hip_runtime.h>
#include <hip/hip_bf16.h>

namespace {

typedef _Float16 h16;
typedef _Float16 f16x8 __attribute__((ext_vector_type(8)));
typedef _Float16 f16x4 __attribute__((ext_vector_type(4)));
typedef _Float16 f16x2 __attribute__((ext_vector_type(2)));
typedef float    f32x4 __attribute__((ext_vector_type(4)));

constexpr int T_SEQ = 512;
constexpr int B_SZ  = 1024;
constexpr int H_DIM = 128;
constexpr int ROWS  = 16;    // batch rows per block (MFMA N-tile)
constexpr int NT    = 512;   // 8 waves
constexpr int KSH   = 4;     // K-steps over h (128/32)
constexpr int KSX0  = 2;     // l0 input K-steps (64/32)
constexpr int KSX1  = 4;     // l1 input K-steps (128/32)
// Row strides: 16B-aligned rows (b128-friendly) AND <=2 lanes/bank on frag
// reads (stride/4 == 4 mod 32 dwords). Round-5 (fast) config; round-8's +4
// pad broke 16B alignment and regressed.
constexpr int ROWP0 = 192 + 8;  // 400 B/row
constexpr int ROWP1 = 256 + 8;  // 528 B/row

// Fused 2-layer persistent GRU. Block owns 16 batch rows; 8 waves.
// Global step g: l0 computes h1(g) from {h1(g-1), x(g)} in hx0[cur];
// l1 computes h2(g-1) from {h2(g-2), h1(g-1)} in hx1[cur]. l0 writes h1(g)
// into hx1[cur^1].input -> l1 consumes it next step. One barrier per step;
// 513 steps total instead of 1024 serial ones; h1 never touches HBM.
// Frag convention verified on HW (rounds 4-8, absmax 1.2e-4):
//  A row = lane&15 (gate in tile), k = (lane>>4)*8 + e + 32*ks
//  B col = lane&15 (batch), same k;  D: col = lane&15, row = (lane>>4)*4 + i
__global__ __launch_bounds__(NT, 1)
void gru2(const float* __restrict__ x,      // [B][T][64] f32
          const float* __restrict__ w_ih0,  // [384][64]
          const float* __restrict__ w_hh0,  // [384][128]
          const float* __restrict__ b_ih0, const float* __restrict__ b_hh0,
          const float* __restrict__ w_ih1,  // [384][128]
          const float* __restrict__ w_hh1,  // [384][128]
          const float* __restrict__ b_ih1, const float* __restrict__ b_hh1,
          float* __restrict__ h2out)        // [B][128]
{
  __shared__ __align__(16) h16 hx0[2][ROWS][ROWP0]; // [h1-state(128) | x(64) | pad]
  __shared__ __align__(16) h16 hx1[2][ROWS][ROWP1]; // [h2-state(128) | h1-in(128) | pad]

  const int tid = threadIdx.x;
  const int wv  = tid >> 6;        // wave 0..7 -> 16-gate-col group
  const int ln  = tid & 63;
  const int q   = ln >> 4;
  const int lr  = ln & 15;
  const int r0  = blockIdx.x * ROWS;
  const int j0  = wv * 16 + q * 4;

  auto ldw = [](const float* pw) {
    const float4 v0 = *(const float4*)(pw);
    const float4 v1 = *(const float4*)(pw + 4);
    f16x8 f;
    f[0]=(h16)v0.x; f[1]=(h16)v0.y; f[2]=(h16)v0.z; f[3]=(h16)v0.w;
    f[4]=(h16)v1.x; f[5]=(h16)v1.y; f[6]=(h16)v1.z; f[7]=(h16)v1.w;
    return f;
  };

  // ---- weights -> fp16 MFMA A-frags (AGPR-resident; MFMA reads them free) ----
  f16x8 wA0[3][KSH], wB0[3][KSX0], wA1[3][KSH], wB1[3][KSX1];
  #pragma unroll
  for (int p = 0; p < 3; ++p) {
    const int g = p * H_DIM + wv * 16 + lr;
    #pragma unroll
    for (int ks = 0; ks < KSH; ++ks) {
      wA0[p][ks] = ldw(w_hh0 + (size_t)g * H_DIM + ks * 32 + q * 8);
      wA1[p][ks] = ldw(w_hh1 + (size_t)g * H_DIM + ks * 32 + q * 8);
    }
    #pragma unroll
    for (int ks = 0; ks < KSX0; ++ks)
      wB0[p][ks] = ldw(w_ih0 + (size_t)g * 64 + ks * 32 + q * 8);
    #pragma unroll
    for (int ks = 0; ks < KSX1; ++ks)
      wB1[p][ks] = ldw(w_ih1 + (size_t)g * H_DIM + ks * 32 + q * 8);
  }

  // ---- biases folded into MFMA C-init (per layer) ----
  f32x4 bR0, bZ0, bNx0, bNh0, bR1, bZ1, bNx1, bNh1;
  {
    auto mkb = [&](const float* bi, const float* bh,
                   f32x4& bR, f32x4& bZ, f32x4& bNx, f32x4& bNh) {
      const float4 ir  = *(const float4*)&bi[j0];
      const float4 hr  = *(const float4*)&bh[j0];
      const float4 iz  = *(const float4*)&bi[H_DIM + j0];
      const float4 hz  = *(const float4*)&bh[H_DIM + j0];
      const float4 in_ = *(const float4*)&bi[2 * H_DIM + j0];
      const float4 hn  = *(const float4*)&bh[2 * H_DIM + j0];
      bR[0]=ir.x+hr.x; bR[1]=ir.y+hr.y; bR[2]=ir.z+hr.z; bR[3]=ir.w+hr.w;
      bZ[0]=iz.x+hz.x; bZ[1]=iz.y+hz.y; bZ[2]=iz.z+hz.z; bZ[3]=iz.w+hz.w;
      bNx[0]=in_.x; bNx[1]=in_.y; bNx[2]=in_.z; bNx[3]=in_.w;
      bNh[0]=hn.x;  bNh[1]=hn.y;  bNh[2]=hn.z;  bNh[3]=hn.w;
    };
    mkb(b_ih0, b_hh0, bR0, bZ0, bNx0, bNh0);
    mkb(b_ih1, b_hh1, bR1, bZ1, bNx1, bNh1);
  }

  const int sr = tid >> 5;   // 0..15
  const int si = tid & 31;   // 0..31

  // ---- prologue: zero h-states, stage x(0), prefetch x(1) ----
  {
    f16x4 z; z[0]=z[1]=z[2]=z[3] = (h16)0.f;
    *(f16x4*)&hx0[0][tid >> 5][(tid & 31) * 4] = z;  // h1(-1) = 0
    *(f16x4*)&hx1[1][tid >> 5][(tid & 31) * 4] = z;  // h2(-1) = 0
  }
  {
    const float2 v = *(const float2*)(x + ((size_t)(r0 + sr) * T_SEQ + 0) * 64 + si * 2);
    f16x2 s0; s0[0] = (h16)v.x; s0[1] = (h16)v.y;
    *(f16x2*)&hx0[0][sr][H_DIM + si * 2] = s0;
  }
  f16x2 sA, sB;
  {
    const float2 v = *(const float2*)(x + ((size_t)(r0 + sr) * T_SEQ + 1) * 64 + si * 2);
    sA[0] = (h16)v.x; sA[1] = (h16)v.y;
  }
  f16x4 h_old0, h_old1;
  h_old0[0]=h_old0[1]=h_old0[2]=h_old0[3] = (h16)0.f;
  h_old1 = h_old0;
  __syncthreads();

  // ---- shared gate math ----
  auto gates = [&](const f32x4& aR, const f32x4& aZ, const f32x4& aNx, const f32x4& aNh,
                   f16x4& h_old, float* hnv) -> f16x4 {
    f16x4 nv4;
    #pragma unroll
    for (int i = 0; i < 4; ++i) {
      const float rg = __builtin_amdgcn_rcpf(1.f + __expf(-aR[i]));
      const float zg = __builtin_amdgcn_rcpf(1.f + __expf(-aZ[i]));
      const float na = aNx[i] + rg * aNh[i];
      const float e2 = __expf(2.f * na);
      const float ng = 1.f - 2.f * __builtin_amdgcn_rcpf(e2 + 1.f);
      const float ho = (float)h_old[i];
      const float hn = ng + zg * (ho - ng);
      hnv[i] = hn;
      nv4[i] = (h16)hn;
    }
    h_old = nv4;
    return nv4;
  };

  // ---- l0: compute h1(g); write to hx0[cur^1].h and hx1[cur^1].input ----
  auto l0_step = [&](int g, int cur, f16x2& s_use, f16x2& s_load) {
    f16x8 bh[KSH], bx[KSX0];
    #pragma unroll
    for (int ks = 0; ks < KSH; ++ks)
      bh[ks] = *(const f16x8*)&hx0[cur][lr][ks * 32 + q * 8];
    #pragma unroll
    for (int ks = 0; ks < KSX0; ++ks)
      bx[ks] = *(const f16x8*)&hx0[cur][lr][H_DIM + ks * 32 + q * 8];

    {  // prefetch x(g+2), 2-deep
      const int tt = (g + 2 < T_SEQ) ? g + 2 : T_SEQ - 1;
      const float2 v = *(const float2*)(x + ((size_t)(r0 + sr) * T_SEQ + tt) * 64 + si * 2);
      s_load[0] = (h16)v.x; s_load[1] = (h16)v.y;
    }

    f32x4 aR = bR0, aZ = bZ0, aNh = bNh0, aNx = bNx0;
    #pragma unroll
    for (int ks = 0; ks < KSH; ++ks) {
      aR  = __builtin_amdgcn_mfma_f32_16x16x32_f16(wA0[0][ks], bh[ks], aR, 0, 0, 0);
      aZ  = __builtin_amdgcn_mfma_f32_16x16x32_f16(wA0[1][ks], bh[ks], aZ, 0, 0, 0);
      aNh = __builtin_amdgcn_mfma_f32_16x16x32_f16(wA0[2][ks], bh[ks], aNh, 0, 0, 0);
    }
    #pragma unroll
    for (int ks = 0; ks < KSX0; ++ks) {
      aR  = __builtin_amdgcn_mfma_f32_16x16x32_f16(wB0[0][ks], bx[ks], aR, 0, 0, 0);
      aZ  = __builtin_amdgcn_mfma_f32_16x16x32_f16(wB0[1][ks], bx[ks], aZ, 0, 0, 0);
      aNx = __builtin_amdgcn_mfma_f32_16x16x32_f16(wB0[2][ks], bx[ks], aNx, 0, 0, 0);
    }

    float hnv[4];
    const f16x4 nv4 = gates(aR, aZ, aNx, aNh, h_old0, hnv);
    *(f16x4*)&hx0[cur ^ 1][lr][j0] = nv4;            // h1 state
    *(f16x4*)&hx1[cur ^ 1][lr][H_DIM + j0] = nv4;    // l1's input next step
    *(f16x2*)&hx0[cur ^ 1][sr][H_DIM + si * 2] = s_use;
  };

  // ---- l1: compute h2(g-1) from hx1[cur]; FINAL=true stores h2out ----
  auto l1_step = [&](int cur, bool final_store) {
    f16x8 bh[KSH], bx[KSX1];
    #pragma unroll
    for (int ks = 0; ks < KSH; ++ks)
      bh[ks] = *(const f16x8*)&hx1[cur][lr][ks * 32 + q * 8];
    #pragma unroll
    for (int ks = 0; ks < KSX1; ++ks)
      bx[ks] = *(const f16x8*)&hx1[cur][lr][H_DIM + ks * 32 + q * 8];

    f32x4 aR = bR1, aZ = bZ1, aNh = bNh1, aNx = bNx1;
    #pragma unroll
    for (int ks = 0; ks < KSH; ++ks) {
      aR  = __builtin_amdgcn_mfma_f32_16x16x32_f16(wA1[0][ks], bh[ks], aR, 0, 0, 0);
      aZ  = __builtin_amdgcn_mfma_f32_16x16x32_f16(wA1[1][ks], bh[ks], aZ, 0, 0, 0);
      aNh = __builtin_amdgcn_mfma_f32_16x16x32_f16(wA1[2][ks], bh[ks], aNh, 0, 0, 0);
    }
    #pragma unroll
    for (int ks = 0; ks < KSX1; ++ks) {
      aR  = __builtin_amdgcn_mfma_f32_16x16x32_f16(wB1[0][ks], bx[ks], aR, 0, 0, 0);
      aZ  = __builtin_amdgcn_mfma_f32_16x16x32_f16(wB1[1][ks], bx[ks], aZ, 0, 0, 0);
      aNx = __builtin_amdgcn_mfma_f32_16x16x32_f16(wB1[2][ks], bx[ks], aNx, 0, 0, 0);
    }

    float hnv[4];
    const f16x4 nv4 = gates(aR, aZ, aNx, aNh, h_old1, hnv);
    *(f16x4*)&hx1[cur ^ 1][lr][j0] = nv4;            // h2 state
    if (final_store)
      *(float4*)&h2out[(size_t)(r0 + lr) * H_DIM + j0] =
          make_float4(hnv[0], hnv[1], hnv[2], hnv[3]);
  };

  // ---- pipeline: g=0 (l0 only); g=1..511 (both); g=512 (l1 only) ----
  l0_step(0, 0, sA, sB);
  __syncthreads();

  #pragma unroll 1
  for (int k = 0; k < (T_SEQ - 2) / 2; ++k) {     // g = 1..510
    l0_step(2 * k + 1, 1, sB, sA);
    l1_step(1, false);
    __syncthreads();
    l0_step(2 * k + 2, 0, sA, sB);
    l1_step(0, false);
    __syncthreads();
  }
  l0_step(T_SEQ - 1, 1, sB, sA);                  // g = 511
  l1_step(1, false);
  __syncthreads();
  l1_step(0, true);                               // g = 512: h2(511) -> out
}

// FC head: out = fc2( BN( relu( fc1(h2_last) ) ) ); one row per block.
__global__ __launch_bounds__(64)
void head_kernel(const float* __restrict__ h2,
                 const float* __restrict__ fc1_w, const float* __restrict__ fc1_b,
                 const float* __restrict__ fc2_w, const float* __restrict__ fc2_b,
                 const float* __restrict__ gamma, const float* __restrict__ beta,
                 const float* __restrict__ mean,  const float* __restrict__ var,
                 float* __restrict__ out)
{
  const int row = blockIdx.x;
  const int j   = threadIdx.x;
  __shared__ __align__(16) float hrow[H_DIM];
  __shared__ __align__(16) float act[64];

  hrow[j]      = h2[(size_t)row * H_DIM + j];
  hrow[64 + j] = h2[(size_t)row * H_DIM + 64 + j];
  __syncthreads();

  float s = fc1_b[j];
  const float4* wr = reinterpret_cast<const float4*>(fc1_w + (size_t)j * H_DIM);
  #pragma unroll
  for (int k4 = 0; k4 < H_DIM / 4; ++k4) {
    const float4 w = wr[k4];
    const float4 h = reinterpret_cast<const float4*>(hrow)[k4];
    s += w.x * h.x + w.y * h.y + w.z * h.z + w.w * h.w;
  }
  s = fmaxf(s, 0.f);
  s = (s - mean[j]) * rsqrtf(var[j] + 1e-5f) * gamma[j] + beta[j];
  act[j] = s;
  __syncthreads();

  if (j < 2) {
    float o = fc2_b[j];
    #pragma unroll
    for (int k = 0; k < 64; ++k) o += fc2_w[(size_t)j * 64 + k] * act[k];
    out[(size_t)row * 2 + j] = o;
  }
}

} // namespace

extern "C" void kernel_launch(void* const* d_in, const int* in_sizes, int n_in,
                              void* d_out, int out_size, void* d_ws, size_t ws_size,
                              hipStream_t stream) {
  const float* x     = (const float*)d_in[0];
  const float* w_ih0 = (const float*)d_in[1];
  const float* w_hh0 = (const float*)d_in[2];
  const float* b_ih0 = (const float*)d_in[3];
  const float* b_hh0 = (const float*)d_in[4];
  const float* w_ih1 = (const float*)d_in[5];
  const float* w_hh1 = (const float*)d_in[6];
  const float* b_ih1 = (const float*)d_in[7];
  const float* b_hh1 = (const float*)d_in[8];
  const float* fc1_w = (const float*)d_in[9];
  const float* fc1_b = (const float*)d_in[10];
  const float* fc2_w = (const float*)d_in[11];
  const float* fc2_b = (const float*)d_in[12];
  const float* gamma = (const float*)d_in[13];
  const float* beta  = (const float*)d_in[14];
  const float* mean  = (const float*)d_in[15];
  const float* var   = (const float*)d_in[16];
  float* out = (float*)d_out;

  const size_t h2_bytes = (size_t)B_SZ * H_DIM * sizeof(float);  // 512 KB
  if (ws_size < h2_bytes) return;  // fail visibly
  float* h2 = (float*)d_ws;

  gru2<<<dim3(B_SZ / ROWS), dim3(NT), 0, stream>>>(
      x, w_ih0, w_hh0, b_ih0, b_hh0, w_ih1, w_hh1, b_ih1, b_hh1, h2);
  head_kernel<<<dim3(B_SZ), dim3(64), 0, stream>>>(
      h2, fc1_w, fc1_b, fc2_w, fc2_b, gamma, beta, mean, var, out);
}